// Round 6
// baseline (568.886 us; speedup 1.0000x reference)
//
#include <hip/hip_runtime.h>

#define N_PTS 131072
#define TILE 64
#define THREADS 512

typedef __bf16 bf16;
typedef __bf16 bf16x8 __attribute__((ext_vector_type(8)));
typedef float f32x4 __attribute__((ext_vector_type(4)));

// ---------------- workspace layout (bytes) ----------------
#define WS_PERM_OFF   256                       // int perm[N_PTS]
#define WS_WPACK_OFF  (256 + N_PTS * 4)         // = 524544, bf16 packed weights
// packed-weight element offsets (bf16 elements, all [out][K] "transposed")
#define OFF_W0     0          // [256][64]   (k=63 zero pad)
#define OFF_WS     16384      // [3][256][256]
#define OFF_TW0    212992     // [4][256][320] (k: 0..62 pts, 63 zero, 64..319 h)
#define OFF_TWS    540672     // [12][256][256]
#define OFF_FEATW  1327104    // [4][256][256]
#define OFF_VIEWSW 1589248    // [4][128][288] (k: 0..255 feat, 256..282 views, 283..287 zero)
#define TOTAL_PACK 1736704

// ---------------- LDS layout (bytes) ----------------
// Ping-pong H buffers: every layer reads src, writes dst, src != dst ->
// ONE barrier per layer (after epilogue) instead of two. Round-5 had ~21
// lockstep barrier drains; this has ~13.
#define PTS_BASE 0       // [64][64]  bf16, stride 128 (pts; later views cols 0..31)
#define HA_BASE  8192    // [64][256] bf16, stride 512
#define HB_BASE  40960   // [64][256] bf16, stride 512
#define LDS_BYTES 73728

__device__ __forceinline__ unsigned swz(unsigned base, unsigned row, unsigned rowstride,
                                        unsigned kbyte) {
  return (base + row * rowstride + kbyte) ^ ((row & 7u) << 4);
}

// ================= weight pack: fp32 -> bf16, [K][out] -> [out][K] =================
__global__ void k_pack(const float* __restrict__ W0, const float* __restrict__ Ws,
                       const float* __restrict__ tW0, const float* __restrict__ tWs,
                       const float* __restrict__ featW, const float* __restrict__ viewsW,
                       bf16* __restrict__ out, int* __restrict__ ctrl) {
  if (blockIdx.x == 0 && threadIdx.x < 64) ctrl[threadIdx.x] = 0;  // zero ctrl (pre-count)
  for (int idx = blockIdx.x * blockDim.x + threadIdx.x; idx < TOTAL_PACK;
       idx += gridDim.x * blockDim.x) {
    float v;
    if (idx < OFF_WS) {
      int o = idx >> 6, k = idx & 63;
      v = (k < 63) ? W0[k * 256 + o] : 0.f;
    } else if (idx < OFF_TW0) {
      int i = idx - OFF_WS; int l = i >> 16, r = i & 65535, o = r >> 8, k = r & 255;
      v = Ws[l * 65536 + k * 256 + o];
    } else if (idx < OFF_TWS) {
      int i = idx - OFF_TW0; int h = i / 81920, r = i % 81920, o = r / 320, k = r % 320;
      v = (k < 63) ? tW0[(h * 319 + k) * 256 + o]
                   : (k == 63 ? 0.f : tW0[(h * 319 + k - 1) * 256 + o]);
    } else if (idx < OFF_FEATW) {
      int i = idx - OFF_TWS; int hj = i >> 16, r = i & 65535, o = r >> 8, k = r & 255;
      v = tWs[(hj * 256 + k) * 256 + o];
    } else if (idx < OFF_VIEWSW) {
      int i = idx - OFF_FEATW; int h = i >> 16, r = i & 65535, o = r >> 8, k = r & 255;
      v = featW[(h * 256 + k) * 256 + o];
    } else {
      int i = idx - OFF_VIEWSW; int h = i / 36864, r = i % 36864, o = r / 288, k = r % 288;
      v = (k < 283) ? viewsW[(h * 283 + k) * 128 + o] : 0.f;
    }
    out[idx] = (bf16)v;
  }
}

// ================= bucketing =================
// ctrl ints: [0..3]=counts [8..12]=offsets [16..19]=cursor [24..28]=tile_base
__global__ void k_count(const int* __restrict__ head, int* __restrict__ c) {
  __shared__ int lc[4];
  if (threadIdx.x < 4) lc[threadIdx.x] = 0;
  __syncthreads();
  int p = blockIdx.x * 256 + threadIdx.x;
  if (p < N_PTS) atomicAdd(&lc[head[p]], 1);
  __syncthreads();
  if (threadIdx.x < 4 && lc[threadIdx.x]) atomicAdd(&c[threadIdx.x], lc[threadIdx.x]);
}

__global__ void k_scan(int* c) {
  c[8] = 0; c[24] = 0;
  for (int h = 0; h < 4; ++h) {
    c[8 + h + 1] = c[8 + h] + c[h];
    c[16 + h] = c[8 + h];
    c[24 + h + 1] = c[24 + h] + (c[h] + TILE - 1) / TILE;
  }
}

__global__ void k_scatter(const int* __restrict__ head, int* __restrict__ c,
                          int* __restrict__ perm) {
  int p = blockIdx.x * 256 + threadIdx.x;
  int h = (p < N_PTS) ? head[p] : -1;
  int lane = threadIdx.x & 63;
  #pragma unroll
  for (int hh = 0; hh < 4; ++hh) {
    unsigned long long m = __ballot(h == hh);
    if (m == 0ull) continue;
    int leader = __builtin_ctzll(m);
    int base = 0;
    if (lane == leader) base = atomicAdd(&c[16 + hh], __popcll(m));
    base = __shfl(base, leader);
    if (h == hh) {
      int rank = __popcll(m & ((1ull << lane) - 1ull));
      perm[base + rank] = p;
    }
  }
}

// ================= fused MLP layer (MFMA, ping-pong) =================
// A from LDS (regions a0 then a1), B = packed bf16 [out][wK] in global.
// 8 waves; each wave computes 64 rows x NFRAG*16 cols. dst != src, so the
// epilogue writes immediately and ONE barrier ends the layer.
//
// K-loop: `#pragma unroll 1` (full unroll let the scheduler hoist all B
// loads -> 200-reg demand -> 422 MB spill in round 4) + manual 2-deep B
// prefetch (1-deep left ~200-400cy L2 latency exposed in round 5).
template <int NFRAG, bool RELU, int A0KC, int A1KC>
__device__ __forceinline__ void mfma_layer(char* lds, const bf16* __restrict__ Wt, int wK,
                                           const float* __restrict__ bias,
                                           int a0_base, int a0_stride,
                                           int a1_base, int a1_stride,
                                           int out_base, int out_stride,
                                           int lane, int wave) {
  const int l15 = lane & 15, l4 = lane >> 4;
  constexpr int KC = A0KC + A1KC;
  f32x4 acc[4][NFRAG];
  #pragma unroll
  for (int m = 0; m < 4; ++m)
    #pragma unroll
    for (int n = 0; n < NFRAG; ++n) acc[m][n] = (f32x4){0.f, 0.f, 0.f, 0.f};

  const int c0 = wave * (NFRAG * 16);
  const bf16* bp = Wt + (c0 + l15) * wK + l4 * 8;  // n advances by nstep elements
  const int nstep = 16 * wK;

  bf16x8 bc[NFRAG], bn[NFRAG];
  #pragma unroll
  for (int n = 0; n < NFRAG; ++n) bc[n] = *(const bf16x8*)(bp + n * nstep);
  constexpr int K1 = (KC > 1) ? 32 : 0;
  #pragma unroll
  for (int n = 0; n < NFRAG; ++n) bn[n] = *(const bf16x8*)(bp + n * nstep + K1);

  #pragma unroll 1
  for (int kc = 0; kc < KC; ++kc) {
    const int kf = (kc + 2 < KC) ? kc + 2 : KC - 1;   // 2-deep prefetch (clamped)
    bf16x8 bf_[NFRAG];
    #pragma unroll
    for (int n = 0; n < NFRAG; ++n) bf_[n] = *(const bf16x8*)(bp + n * nstep + kf * 32);

    const int base   = (kc < A0KC) ? a0_base   : a1_base;
    const int stride = (kc < A0KC) ? a0_stride : a1_stride;
    const int kl     = ((kc < A0KC) ? kc : kc - A0KC) * 32;
    bf16x8 a[4];
    #pragma unroll
    for (int m = 0; m < 4; ++m)
      a[m] = *(const bf16x8*)(lds + swz(base, m * 16 + l15, stride, (kl + l4 * 8) * 2));

    #pragma unroll
    for (int n = 0; n < NFRAG; ++n)
      #pragma unroll
      for (int m = 0; m < 4; ++m)
        acc[m][n] = __builtin_amdgcn_mfma_f32_16x16x32_bf16(a[m], bc[n], acc[m][n], 0, 0, 0);

    #pragma unroll
    for (int n = 0; n < NFRAG; ++n) { bc[n] = bn[n]; bn[n] = bf_[n]; }
  }

  // epilogue: dst disjoint from src -> write immediately
  #pragma unroll
  for (int n = 0; n < NFRAG; ++n) {
    int col = c0 + n * 16 + l15;
    float bv = bias[col];
    #pragma unroll
    for (int m = 0; m < 4; ++m) {
      #pragma unroll
      for (int j = 0; j < 4; ++j) {
        float v = acc[m][n][j] + bv;
        if (RELU) v = fmaxf(v, 0.f);
        int row = m * 16 + l4 * 4 + j;
        *(bf16*)(lds + swz(out_base, row, out_stride, col * 2)) = (bf16)v;
      }
    }
  }
  __syncthreads();
}

// ================= main fused kernel =================
// 8 waves x (64 rows x 32 cols); (512,4) = 128-reg budget, 16 waves/CU.
__global__ __launch_bounds__(THREADS, 4) void k_main(
    const float* __restrict__ x, const int* __restrict__ ctrl, const int* __restrict__ perm,
    const bf16* __restrict__ wpack,
    const float* __restrict__ b0, const float* __restrict__ bs,
    const float* __restrict__ tb0p, const float* __restrict__ tbsp,
    const float* __restrict__ featb, const float* __restrict__ alphaW,
    const float* __restrict__ alphab, const float* __restrict__ viewsb,
    const float* __restrict__ rgbW, const float* __restrict__ rgbb,
    float* __restrict__ outp) {
  __shared__ __attribute__((aligned(16))) char lds[LDS_BYTES];
  __shared__ int pidx[TILE];
  __shared__ float alpha_s[TILE];

  const int tid = threadIdx.x;
  const int lane = tid & 63, wave = tid >> 6;

  // ---- resolve head + tile from control block ----
  const int tbA = ctrl[24], tbB = ctrl[25], tbC = ctrl[26], tbD = ctrl[27], tbE = ctrl[28];
  const int bid = blockIdx.x;
  if (bid >= tbE) return;
  const int hh = (bid >= tbB) + (bid >= tbC) + (bid >= tbD);
  const int tb_h = (hh == 0) ? tbA : ((hh == 1) ? tbB : ((hh == 2) ? tbC : tbD));
  const int start = ctrl[8 + hh] + (bid - tb_h) * TILE;
  const int nv = min(TILE, ctrl[8 + hh + 1] - start);

  if (tid < TILE) pidx[tid] = (tid < nv) ? perm[start + tid] : -1;
  __syncthreads();

  // ---- stage 1: pts -> LDS bf16 [64][64] (col 63 = 0, rows>=nv = 0) ----
  for (int i = tid; i < TILE * 64; i += THREADS) {
    int row = i >> 6, c = i & 63;
    int p = pidx[row];
    float v = (p >= 0 && c < 63) ? x[p * 90 + c] : 0.f;
    *(bf16*)(lds + swz(PTS_BASE, row, 128, c * 2)) = (bf16)v;
  }
  __syncthreads();

  const bf16* W0p    = wpack + OFF_W0;
  const bf16* Wsp    = wpack + OFF_WS;
  const bf16* tW0p   = wpack + OFF_TW0 + hh * 81920;
  const bf16* tWsp   = wpack + OFF_TWS + hh * 3 * 65536;
  const bf16* featWp = wpack + OFF_FEATW + hh * 65536;
  const bf16* viewsWp= wpack + OFF_VIEWSW + hh * 36864;

  // trunk (ping-pong): PTS->HA, HA->HB, HB->HA, HA->HB
  mfma_layer<2, true, 2, 0>(lds, W0p, 64, b0, PTS_BASE, 128, 0, 0, HA_BASE, 512, lane, wave);
  mfma_layer<2, true, 8, 0>(lds, Wsp,           256, bs,       HA_BASE, 512, 0, 0, HB_BASE, 512, lane, wave);
  mfma_layer<2, true, 8, 0>(lds, Wsp + 65536,   256, bs + 256, HB_BASE, 512, 0, 0, HA_BASE, 512, lane, wave);
  mfma_layer<2, true, 8, 0>(lds, Wsp + 131072,  256, bs + 512, HA_BASE, 512, 0, 0, HB_BASE, 512, lane, wave);
  // T0: concat(pts, h=HB) 320 -> 256, into HA
  mfma_layer<2, true, 2, 8>(lds, tW0p, 320, tb0p + hh * 256,
                            PTS_BASE, 128, HB_BASE, 512, HA_BASE, 512, lane, wave);

  // ---- stage 2: views -> PTS cols 0..31 (T0's reads of PTS are barrier-complete;
  //      next reader is the views layer, 4 barriers later) ----
  for (int i = tid; i < TILE * 32; i += THREADS) {
    int row = i >> 5, c = i & 31;
    int p = pidx[row];
    float v = (p >= 0 && c < 27) ? x[p * 90 + 63 + c] : 0.f;
    *(bf16*)(lds + swz(PTS_BASE, row, 128, c * 2)) = (bf16)v;
  }

  // head layers: HA->HB, HB->HA, HA->HB
  mfma_layer<2, true, 8, 0>(lds, tWsp,          256, tbsp + hh * 768,       HA_BASE, 512, 0, 0, HB_BASE, 512, lane, wave);
  mfma_layer<2, true, 8, 0>(lds, tWsp + 65536,  256, tbsp + hh * 768 + 256, HB_BASE, 512, 0, 0, HA_BASE, 512, lane, wave);
  mfma_layer<2, true, 8, 0>(lds, tWsp + 131072, 256, tbsp + hh * 768 + 512, HA_BASE, 512, 0, 0, HB_BASE, 512, lane, wave);

  // ---- alpha = ha(HB) . alphaW[hh] + alphab (waves 0-3; safe until views epi) ----
  if (wave < 4) {
    int p = wave * 16 + (lane & 15);
    int kq = lane >> 4;
    const float* aW = alphaW + hh * 256;
    float s = 0.f;
    for (int i = 0; i < 8; ++i) {
      int k = kq * 64 + i * 8;
      bf16x8 hv8 = *(const bf16x8*)(lds + swz(HB_BASE, p, 512, k * 2));
      #pragma unroll
      for (int j = 0; j < 8; ++j) s += (float)hv8[j] * aW[k + j];
    }
    s += __shfl_xor(s, 16);
    s += __shfl_xor(s, 32);
    if (kq == 0) alpha_s[p] = s + alphab[hh];
  }

  // feat: HB -> HA, NO relu
  mfma_layer<2, false, 8, 0>(lds, featWp, 256, featb + hh * 256,
                             HB_BASE, 512, 0, 0, HA_BASE, 512, lane, wave);
  // views: concat(feat=HA, views=PTS cols 0..31) 288 -> 128, relu, into HB
  mfma_layer<1, true, 8, 1>(lds, viewsWp, 288, viewsb + hh * 128,
                            HA_BASE, 512, PTS_BASE, 128, HB_BASE, 512, lane, wave);

  // ---- rgb = hv(HB) . rgbW[hh] + rgbb ; write float4 {r,g,b,alpha} (waves 0-3) ----
  if (wave < 4) {
    int p = wave * 16 + (lane & 15);
    int kq = lane >> 4;
    const float* rW = rgbW + hh * 128 * 3;
    float r0 = 0.f, r1 = 0.f, r2 = 0.f;
    for (int i = 0; i < 4; ++i) {
      int k = kq * 32 + i * 8;
      bf16x8 hv8 = *(const bf16x8*)(lds + swz(HB_BASE, p, 512, k * 2));
      #pragma unroll
      for (int j = 0; j < 8; ++j) {
        float hvf = (float)hv8[j];
        r0 += hvf * rW[(k + j) * 3 + 0];
        r1 += hvf * rW[(k + j) * 3 + 1];
        r2 += hvf * rW[(k + j) * 3 + 2];
      }
    }
    r0 += __shfl_xor(r0, 16); r0 += __shfl_xor(r0, 32);
    r1 += __shfl_xor(r1, 16); r1 += __shfl_xor(r1, 32);
    r2 += __shfl_xor(r2, 16); r2 += __shfl_xor(r2, 32);
    if (kq == 0 && p < nv) {
      int pt = pidx[p];
      float4 o = make_float4(r0 + rgbb[hh * 3 + 0], r1 + rgbb[hh * 3 + 1],
                             r2 + rgbb[hh * 3 + 2], alpha_s[p]);
      *(float4*)(outp + pt * 4) = o;
    }
  }
}

// ================= launch =================
extern "C" void kernel_launch(void* const* d_in, const int* in_sizes, int n_in,
                              void* d_out, int out_size, void* d_ws, size_t ws_size,
                              hipStream_t stream) {
  const float* x      = (const float*)d_in[0];
  const int*   head   = (const int*)d_in[1];
  const float* W0     = (const float*)d_in[2];
  const float* b0     = (const float*)d_in[3];
  const float* Ws     = (const float*)d_in[4];
  const float* bs     = (const float*)d_in[5];
  const float* tW0    = (const float*)d_in[6];
  const float* tb0    = (const float*)d_in[7];
  const float* tWs    = (const float*)d_in[8];
  const float* tbs    = (const float*)d_in[9];
  const float* featW  = (const float*)d_in[10];
  const float* featb  = (const float*)d_in[11];
  const float* alphaW = (const float*)d_in[12];
  const float* alphab = (const float*)d_in[13];
  const float* viewsW = (const float*)d_in[14];
  const float* viewsb = (const float*)d_in[15];
  const float* rgbW   = (const float*)d_in[16];
  const float* rgbb   = (const float*)d_in[17];

  int*  ctrl  = (int*)d_ws;
  int*  perm  = (int*)((char*)d_ws + WS_PERM_OFF);
  bf16* wpack = (bf16*)((char*)d_ws + WS_WPACK_OFF);

  k_pack<<<2048, 256, 0, stream>>>(W0, Ws, tW0, tWs, featW, viewsW, wpack, ctrl);
  k_count<<<N_PTS / 256, 256, 0, stream>>>(head, ctrl);
  k_scan<<<1, 1, 0, stream>>>(ctrl);
  k_scatter<<<N_PTS / 256, 256, 0, stream>>>(head, ctrl, perm);
  k_main<<<N_PTS / TILE + 4, THREADS, 0, stream>>>(x, ctrl, perm, wpack,
                                                   b0, bs, tb0, tbs, featb, alphaW, alphab,
                                                   viewsb, rgbW, rgbb, (float*)d_out);
}

// Round 7
// 440.606 us; speedup vs baseline: 1.2911x; 1.2911x over previous
//
#include <hip/hip_runtime.h>

#define N_PTS 131072
#define TILE 64
#define THREADS 512

typedef __bf16 bf16;
typedef __bf16 bf16x8 __attribute__((ext_vector_type(8)));
typedef float f32x4 __attribute__((ext_vector_type(4)));

// ---------------- workspace layout (bytes) ----------------
#define WS_PERM_OFF   256                       // int perm[N_PTS]
#define WS_WPACK_OFF  (256 + N_PTS * 4)         // = 524544, bf16 packed weights
// packed-weight element offsets (bf16 elements, all [out][K] "transposed")
#define OFF_W0     0          // [256][64]   (k=63 zero pad)
#define OFF_WS     16384      // [3][256][256]
#define OFF_TW0    212992     // [4][256][320] (k: 0..62 pts, 63 zero, 64..319 h)
#define OFF_TWS    540672     // [12][256][256]
#define OFF_FEATW  1327104    // [4][256][256]
#define OFF_VIEWSW 1589248    // [4][128][288] (k: 0..255 feat, 256..282 views, 283..287 zero)
#define TOTAL_PACK 1736704

// ---------------- LDS layout (bytes) ----------------
// PTS [64][64]bf16 (stride 128) + in-place H [64][256]bf16 (stride 512)
// + B double-buffer 2 x 16KB (staged via global_load_lds, linear [o][32k]).
// 72KB total -> 2 blocks/CU (160KB): the per-kc barrier drains of one block
// interleave with the other block's compute.
#define PTS_BASE 0
#define H_BASE   8192
#define B_BASE   40960
#define LDS_BYTES 73728

__device__ __forceinline__ unsigned swz(unsigned base, unsigned row, unsigned rowstride,
                                        unsigned kbyte) {
  return (base + row * rowstride + kbyte) ^ ((row & 7u) << 4);
}

// async global->LDS, 16B per lane; LDS dest = wave-uniform base + lane*16
__device__ __forceinline__ void gload_lds16(const bf16* g, char* l) {
  __builtin_amdgcn_global_load_lds(
      (const __attribute__((address_space(1))) void*)g,
      (__attribute__((address_space(3))) void*)l, 16, 0, 0);
}

// ================= weight pack (fp32->bf16 transpose) + head count =================
__global__ void k_pack(const float* __restrict__ W0, const float* __restrict__ Ws,
                       const float* __restrict__ tW0, const float* __restrict__ tWs,
                       const float* __restrict__ featW, const float* __restrict__ viewsW,
                       bf16* __restrict__ out, const int* __restrict__ head,
                       int* __restrict__ ctrl) {
  __shared__ int lc[4];
  if (threadIdx.x < 4) lc[threadIdx.x] = 0;
  __syncthreads();
  int gid = blockIdx.x * blockDim.x + threadIdx.x;
  if (gid < N_PTS) atomicAdd(&lc[head[gid]], 1);

  for (int idx = gid; idx < TOTAL_PACK; idx += gridDim.x * blockDim.x) {
    float v;
    if (idx < OFF_WS) {
      int o = idx >> 6, k = idx & 63;
      v = (k < 63) ? W0[k * 256 + o] : 0.f;
    } else if (idx < OFF_TW0) {
      int i = idx - OFF_WS; int l = i >> 16, r = i & 65535, o = r >> 8, k = r & 255;
      v = Ws[l * 65536 + k * 256 + o];
    } else if (idx < OFF_TWS) {
      int i = idx - OFF_TW0; int h = i / 81920, r = i % 81920, o = r / 320, k = r % 320;
      v = (k < 63) ? tW0[(h * 319 + k) * 256 + o]
                   : (k == 63 ? 0.f : tW0[(h * 319 + k - 1) * 256 + o]);
    } else if (idx < OFF_FEATW) {
      int i = idx - OFF_TWS; int hj = i >> 16, r = i & 65535, o = r >> 8, k = r & 255;
      v = tWs[(hj * 256 + k) * 256 + o];
    } else if (idx < OFF_VIEWSW) {
      int i = idx - OFF_FEATW; int h = i >> 16, r = i & 65535, o = r >> 8, k = r & 255;
      v = featW[(h * 256 + k) * 256 + o];
    } else {
      int i = idx - OFF_VIEWSW; int h = i / 36864, r = i % 36864, o = r / 288, k = r % 288;
      v = (k < 283) ? viewsW[(h * 283 + k) * 128 + o] : 0.f;
    }
    out[idx] = (bf16)v;
  }
  __syncthreads();
  if (threadIdx.x < 4 && lc[threadIdx.x]) atomicAdd(&ctrl[threadIdx.x], lc[threadIdx.x]);
}

// ================= bucketing =================
// ctrl ints: [0..3]=counts [8..12]=offsets [16..19]=cursor [24..28]=tile_base
__global__ void k_scan(int* c) {
  c[8] = 0; c[24] = 0;
  for (int h = 0; h < 4; ++h) {
    c[8 + h + 1] = c[8 + h] + c[h];
    c[16 + h] = c[8 + h];
    c[24 + h + 1] = c[24 + h] + (c[h] + TILE - 1) / TILE;
  }
}

__global__ void k_scatter(const int* __restrict__ head, int* __restrict__ c,
                          int* __restrict__ perm) {
  int p = blockIdx.x * 256 + threadIdx.x;
  int h = (p < N_PTS) ? head[p] : -1;
  int lane = threadIdx.x & 63;
  #pragma unroll
  for (int hh = 0; hh < 4; ++hh) {
    unsigned long long m = __ballot(h == hh);
    if (m == 0ull) continue;
    int leader = __builtin_ctzll(m);
    int base = 0;
    if (lane == leader) base = atomicAdd(&c[16 + hh], __popcll(m));
    base = __shfl(base, leader);
    if (h == hh) {
      int rank = __popcll(m & ((1ull << lane) - 1ull));
      perm[base + rank] = p;
    }
  }
}

// ================= B tile staging (global_load_lds) =================
// Tile = B[o][kk..kk+32), o in [0,OUTS). LDS slot (o,j) at byte o*64+j*16
// holds global k-chunk (j ^ (o&3)): source-side XOR swizzle (LDS dest must
// stay linear for global_load_lds) makes the reader's ds_read 2-way max.
template <int OUTS>
__device__ __forceinline__ void stage_B(const bf16* __restrict__ Wt, int wK, int kk,
                                        char* lds, int bufsel, int wave, int lane) {
  constexpr int ISSUES = OUTS / 128;   // 2 (OUTS=256) or 1 (OUTS=128)
  #pragma unroll
  for (int s = 0; s < ISSUES; ++s) {
    int reg = wave * ISSUES + s;            // 1KB region index
    int o = reg * 16 + (lane >> 2);
    int j = lane & 3;
    const bf16* g = Wt + o * wK + kk + ((j ^ (o & 3)) << 3);
    gload_lds16(g, lds + B_BASE + bufsel * 16384 + reg * 1024);
  }
}

// ================= fused MLP layer (MFMA, LDS-staged B) =================
// A from LDS (a0 region for first A0KC k-chunks, then a1). B double-buffered
// in LDS. In-place output is safe: epilogue runs after the last kc barrier
// (all A reads complete); next layer's head barrier orders the writes.
// B lives in ZERO registers -> no spill at (512,4); rounds 1-6 showed any
// reg-resident B pipeline either spills (budget 128/170) or starves (256+).
template <int NFRAG, bool RELU, int A0KC, int A1KC, int OUTS>
__device__ __forceinline__ void mfma_layer(char* lds, const bf16* __restrict__ Wt, int wK,
                                           const float* __restrict__ bias,
                                           int a0_base, int a0_stride,
                                           int a1_base, int a1_stride,
                                           int out_base, int out_stride,
                                           int lane, int wave) {
  const int l15 = lane & 15, l4 = lane >> 4;
  constexpr int KC = A0KC + A1KC;
  f32x4 acc[4][NFRAG];
  #pragma unroll
  for (int m = 0; m < 4; ++m)
    #pragma unroll
    for (int n = 0; n < NFRAG; ++n) acc[m][n] = (f32x4){0.f, 0.f, 0.f, 0.f};

  const int c0 = wave * (NFRAG * 16);

  stage_B<OUTS>(Wt, wK, 0, lds, 0, wave, lane);
  __syncthreads();   // drains stage(0); also orders prev layer's epilogue/pts writes

  #pragma unroll 1
  for (int kc = 0; kc < KC; ++kc) {
    const int buf = kc & 1;
    if (kc + 1 < KC) stage_B<OUTS>(Wt, wK, (kc + 1) * 32, lds, buf ^ 1, wave, lane);

    const int base   = (kc < A0KC) ? a0_base   : a1_base;
    const int stride = (kc < A0KC) ? a0_stride : a1_stride;
    const int kl     = ((kc < A0KC) ? kc : kc - A0KC) * 32;
    bf16x8 a[4];
    #pragma unroll
    for (int m = 0; m < 4; ++m)
      a[m] = *(const bf16x8*)(lds + swz(base, m * 16 + l15, stride, (kl + l4 * 8) * 2));

    bf16x8 b[NFRAG];
    #pragma unroll
    for (int n = 0; n < NFRAG; ++n) {
      int col = c0 + n * 16 + l15;
      b[n] = *(const bf16x8*)(lds + B_BASE + buf * 16384 + col * 64 + ((l4 ^ (col & 3)) << 4));
    }

    #pragma unroll
    for (int n = 0; n < NFRAG; ++n)
      #pragma unroll
      for (int m = 0; m < 4; ++m)
        acc[m][n] = __builtin_amdgcn_mfma_f32_16x16x32_bf16(a[m], b[n], acc[m][n], 0, 0, 0);

    __syncthreads();  // buf[kc] consumed; stage(kc+1) drained (vmcnt at barrier)
  }

  // epilogue: all reads done (last kc barrier) -> in-place write is safe
  #pragma unroll
  for (int n = 0; n < NFRAG; ++n) {
    int col = c0 + n * 16 + l15;
    float bv = bias[col];
    #pragma unroll
    for (int m = 0; m < 4; ++m) {
      #pragma unroll
      for (int j = 0; j < 4; ++j) {
        float v = acc[m][n][j] + bv;
        if (RELU) v = fmaxf(v, 0.f);
        int row = m * 16 + l4 * 4 + j;
        *(bf16*)(lds + swz(out_base, row, out_stride, col * 2)) = (bf16)v;
      }
    }
  }
  // no trailing barrier: next layer's head barrier (or explicit one) orders it
}

// ================= main fused kernel =================
__global__ __launch_bounds__(THREADS, 4) void k_main(
    const float* __restrict__ x, const int* __restrict__ ctrl, const int* __restrict__ perm,
    const bf16* __restrict__ wpack,
    const float* __restrict__ b0, const float* __restrict__ bs,
    const float* __restrict__ tb0p, const float* __restrict__ tbsp,
    const float* __restrict__ featb, const float* __restrict__ alphaW,
    const float* __restrict__ alphab, const float* __restrict__ viewsb,
    const float* __restrict__ rgbW, const float* __restrict__ rgbb,
    float* __restrict__ outp) {
  __shared__ __attribute__((aligned(16))) char lds[LDS_BYTES];
  __shared__ int pidx[TILE];
  __shared__ float alpha_s[TILE];

  const int tid = threadIdx.x;
  const int lane = tid & 63, wave = tid >> 6;

  // ---- resolve head + tile from control block ----
  const int tbA = ctrl[24], tbB = ctrl[25], tbC = ctrl[26], tbD = ctrl[27], tbE = ctrl[28];
  const int bid = blockIdx.x;
  if (bid >= tbE) return;
  const int hh = (bid >= tbB) + (bid >= tbC) + (bid >= tbD);
  const int tb_h = (hh == 0) ? tbA : ((hh == 1) ? tbB : ((hh == 2) ? tbC : tbD));
  const int start = ctrl[8 + hh] + (bid - tb_h) * TILE;
  const int nv = min(TILE, ctrl[8 + hh + 1] - start);

  if (tid < TILE) pidx[tid] = (tid < nv) ? perm[start + tid] : -1;
  __syncthreads();

  // ---- pts -> LDS bf16 [64][64] (col 63 = 0, rows>=nv = 0) ----
  for (int i = tid; i < TILE * 64; i += THREADS) {
    int row = i >> 6, c = i & 63;
    int p = pidx[row];
    float v = (p >= 0 && c < 63) ? x[p * 90 + c] : 0.f;
    *(bf16*)(lds + swz(PTS_BASE, row, 128, c * 2)) = (bf16)v;
  }
  // (no barrier needed: first layer's head barrier orders these writes)

  const bf16* W0p    = wpack + OFF_W0;
  const bf16* Wsp    = wpack + OFF_WS;
  const bf16* tW0p   = wpack + OFF_TW0 + hh * 81920;
  const bf16* tWsp   = wpack + OFF_TWS + hh * 3 * 65536;
  const bf16* featWp = wpack + OFF_FEATW + hh * 65536;
  const bf16* viewsWp= wpack + OFF_VIEWSW + hh * 36864;

  // trunk: 63->256, 3x 256->256 (in-place H)
  mfma_layer<2, true, 2, 0, 256>(lds, W0p, 64, b0, PTS_BASE, 128, 0, 0, H_BASE, 512, lane, wave);
  mfma_layer<2, true, 8, 0, 256>(lds, Wsp,          256, bs,       H_BASE, 512, 0, 0, H_BASE, 512, lane, wave);
  mfma_layer<2, true, 8, 0, 256>(lds, Wsp + 65536,  256, bs + 256, H_BASE, 512, 0, 0, H_BASE, 512, lane, wave);
  mfma_layer<2, true, 8, 0, 256>(lds, Wsp + 131072, 256, bs + 512, H_BASE, 512, 0, 0, H_BASE, 512, lane, wave);
  // T0: concat(pts, h) 320 -> 256
  mfma_layer<2, true, 2, 8, 256>(lds, tW0p, 320, tb0p + hh * 256,
                                 PTS_BASE, 128, H_BASE, 512, H_BASE, 512, lane, wave);

  // views -> PTS cols 0..31 (T0's PTS reads are complete: bounded by its kc barriers;
  // next reader is the views layer, 4 layers of barriers later)
  for (int i = tid; i < TILE * 32; i += THREADS) {
    int row = i >> 5, c = i & 31;
    int p = pidx[row];
    float v = (p >= 0 && c < 27) ? x[p * 90 + 63 + c] : 0.f;
    *(bf16*)(lds + swz(PTS_BASE, row, 128, c * 2)) = (bf16)v;
  }

  // head layers
  mfma_layer<2, true, 8, 0, 256>(lds, tWsp,          256, tbsp + hh * 768,       H_BASE, 512, 0, 0, H_BASE, 512, lane, wave);
  mfma_layer<2, true, 8, 0, 256>(lds, tWsp + 65536,  256, tbsp + hh * 768 + 256, H_BASE, 512, 0, 0, H_BASE, 512, lane, wave);
  mfma_layer<2, true, 8, 0, 256>(lds, tWsp + 131072, 256, tbsp + hh * 768 + 512, H_BASE, 512, 0, 0, H_BASE, 512, lane, wave);

  __syncthreads();  // headL3 epilogue visible before alpha reads

  // ---- alpha = ha . alphaW[hh] + alphab (waves 0-3; completes before feat's
  //      epilogue because all waves pass feat's kc barriers after this) ----
  if (wave < 4) {
    int p = wave * 16 + (lane & 15);
    int kq = lane >> 4;
    const float* aW = alphaW + hh * 256;
    float s = 0.f;
    for (int i = 0; i < 8; ++i) {
      int k = kq * 64 + i * 8;
      bf16x8 hv8 = *(const bf16x8*)(lds + swz(H_BASE, p, 512, k * 2));
      #pragma unroll
      for (int j = 0; j < 8; ++j) s += (float)hv8[j] * aW[k + j];
    }
    s += __shfl_xor(s, 16);
    s += __shfl_xor(s, 32);
    if (kq == 0) alpha_s[p] = s + alphab[hh];
  }

  // feat: 256->256 in-place, NO relu
  mfma_layer<2, false, 8, 0, 256>(lds, featWp, 256, featb + hh * 256,
                                  H_BASE, 512, 0, 0, H_BASE, 512, lane, wave);
  // views: concat(feat, views[32pad]) 288 -> 128, relu, into H cols 0..127
  mfma_layer<1, true, 8, 1, 128>(lds, viewsWp, 288, viewsb + hh * 128,
                                 H_BASE, 512, PTS_BASE, 128, H_BASE, 512, lane, wave);

  __syncthreads();  // views epilogue visible before rgb reads

  // ---- rgb = hv . rgbW[hh] + rgbb ; write float4 {r,g,b,alpha} (waves 0-3) ----
  if (wave < 4) {
    int p = wave * 16 + (lane & 15);
    int kq = lane >> 4;
    const float* rW = rgbW + hh * 128 * 3;
    float r0 = 0.f, r1 = 0.f, r2 = 0.f;
    for (int i = 0; i < 4; ++i) {
      int k = kq * 32 + i * 8;
      bf16x8 hv8 = *(const bf16x8*)(lds + swz(H_BASE, p, 512, k * 2));
      #pragma unroll
      for (int j = 0; j < 8; ++j) {
        float hvf = (float)hv8[j];
        r0 += hvf * rW[(k + j) * 3 + 0];
        r1 += hvf * rW[(k + j) * 3 + 1];
        r2 += hvf * rW[(k + j) * 3 + 2];
      }
    }
    r0 += __shfl_xor(r0, 16); r0 += __shfl_xor(r0, 32);
    r1 += __shfl_xor(r1, 16); r1 += __shfl_xor(r1, 32);
    r2 += __shfl_xor(r2, 16); r2 += __shfl_xor(r2, 32);
    if (kq == 0 && p < nv) {
      int pt = pidx[p];
      float4 o = make_float4(r0 + rgbb[hh * 3 + 0], r1 + rgbb[hh * 3 + 1],
                             r2 + rgbb[hh * 3 + 2], alpha_s[p]);
      *(float4*)(outp + pt * 4) = o;
    }
  }
}

// ================= launch =================
extern "C" void kernel_launch(void* const* d_in, const int* in_sizes, int n_in,
                              void* d_out, int out_size, void* d_ws, size_t ws_size,
                              hipStream_t stream) {
  const float* x      = (const float*)d_in[0];
  const int*   head   = (const int*)d_in[1];
  const float* W0     = (const float*)d_in[2];
  const float* b0     = (const float*)d_in[3];
  const float* Ws     = (const float*)d_in[4];
  const float* bs     = (const float*)d_in[5];
  const float* tW0    = (const float*)d_in[6];
  const float* tb0    = (const float*)d_in[7];
  const float* tWs    = (const float*)d_in[8];
  const float* tbs    = (const float*)d_in[9];
  const float* featW  = (const float*)d_in[10];
  const float* featb  = (const float*)d_in[11];
  const float* alphaW = (const float*)d_in[12];
  const float* alphab = (const float*)d_in[13];
  const float* viewsW = (const float*)d_in[14];
  const float* viewsb = (const float*)d_in[15];
  const float* rgbW   = (const float*)d_in[16];
  const float* rgbb   = (const float*)d_in[17];

  int*  ctrl  = (int*)d_ws;
  int*  perm  = (int*)((char*)d_ws + WS_PERM_OFF);
  bf16* wpack = (bf16*)((char*)d_ws + WS_WPACK_OFF);

  hipMemsetAsync(ctrl, 0, 256, stream);
  k_pack<<<2048, 256, 0, stream>>>(W0, Ws, tW0, tWs, featW, viewsW, wpack, head, ctrl);
  k_scan<<<1, 1, 0, stream>>>(ctrl);
  k_scatter<<<N_PTS / 256, 256, 0, stream>>>(head, ctrl, perm);
  k_main<<<N_PTS / TILE + 4, THREADS, 0, stream>>>(x, ctrl, perm, wpack,
                                                   b0, bs, tb0, tbs, featb, alphaW, alphab,
                                                   viewsb, rgbW, rgbb, (float*)d_out);
}